// Round 9
// baseline (2136.717 us; speedup 1.0000x reference)
//
#include <hip/hip_runtime.h>
#include <hip/hip_bf16.h>
#include <math.h>

#define DIMD 512
#define SEQL 4096
#define KU 1024
#define KF 1536
#define NJ 8192
#define KC 384          // OpenBLAS sgemm K-blocking (matched in round 5)

#define BM 64
#define BK 32
#define PA 33
#define PW 68

#define GAP_T 1e-3f

// ---- ws layout (bytes) ----
#define WS_R    0u          // 512 f32
#define WS_BC   4096u       // 2*8192 f32 (m-path combined bias, f64-folded)
#define WS_BCE  69632u      // 8192 f32 (e-path combined bias, f64-folded)
#define WS_CNT  102400u     // int counter
#define WS_WL   102656u     // worklist (2.1M ints max)
#define WS_UHI  8491264u    // 4096*1024 bf16
#define WS_ULO  16879872u   // 4096*1024 bf16
#define WS_WHI  25268480u   // 2*8192*1024 bf16 (Wnn,Wno hi)
#define WS_WLO  58822912u   // 2*8192*1024 bf16 (lo)
#define WS_WEH  92377344u   // 8192*1024 bf16 (W_E hi)
#define WS_NEEDED 109154560u

typedef __attribute__((ext_vector_type(8))) short bf16x8;
typedef __attribute__((ext_vector_type(4))) float f32x4;

__device__ __forceinline__ ushort f2bf(float f) {
    __hip_bfloat16 h = __float2bfloat16(f);
    return *reinterpret_cast<ushort*>(&h);
}
__device__ __forceinline__ float bf2f(ushort v) {
    unsigned int b = ((unsigned int)v) << 16;
    return __uint_as_float(b);
}

// XOR swizzle within 128B lines: row-major [rows][32] ushort tile, 16B slots.
// ushort index = r2*64 + phys*8; conflict-free for both staging and b128 reads.
__device__ __forceinline__ int swzi(int row, int c16) {
    int r2 = row >> 1;
    int phys = (((row & 1) << 2) | c16) ^ (r2 & 7);
    return r2 * 64 + phys * 8;
}

// ---- f32 R with the exact chunked fma chain (k-ascending, KC blocks) ----
__device__ __forceinline__ float chainR(
    const float* __restrict__ h, const float* __restrict__ us, const float* __restrict__ ue,
    const float* __restrict__ Wr, const float* __restrict__ br, int o)
{
    float accT = 0.f;
    for (int k0 = 0; k0 < 2560; k0 += KC) {
        int ke = (k0 + KC < 2560) ? k0 + KC : 2560;
        float accC = 0.f;
        for (int k = k0; k < ke; ++k) {
            float xv = (k < 1536) ? h[k] : (k < 2048) ? us[k - 1536] : ue[k - 2048];
            accC = fmaf(xv, Wr[(size_t)o * 2560 + k], accC);
        }
        accT = __fadd_rn(accT, accC);
    }
    return __fadd_rn(accT, br[o]);
}

__global__ __launch_bounds__(256) void k_R32(
    const float* __restrict__ h, const float* __restrict__ us, const float* __restrict__ ue,
    const float* __restrict__ Wr, const float* __restrict__ br, float* __restrict__ Rout)
{
    int o = blockIdx.x * 256 + threadIdx.x;
    Rout[o] = chainR(h, us, ue, Wr, br, o);
}

// ---- prep: u -> bf16 hi/lo ----
__global__ __launch_bounds__(256) void k_prep_u(
    const float* __restrict__ u, ushort* __restrict__ uhi, ushort* __restrict__ ulo)
{
    size_t i4 = (size_t)(blockIdx.x * 256 + threadIdx.x) * 4;
    float4 v = *(const float4*)&u[i4];
    ushort4 a, b;
    a.x = f2bf(v.x); b.x = f2bf(v.x - bf2f(a.x));
    a.y = f2bf(v.y); b.y = f2bf(v.y - bf2f(a.y));
    a.z = f2bf(v.z); b.z = f2bf(v.z - bf2f(a.z));
    a.w = f2bf(v.w); b.w = f2bf(v.w - bf2f(a.w));
    *(ushort4*)&uhi[i4] = a;
    *(ushort4*)&ulo[i4] = b;
}

// ---- prep: Wnn/Wno (k<1024) -> bf16 hi/lo, layout [mat][j][k] ----
__global__ __launch_bounds__(256) void k_prep_w(
    const float* __restrict__ Wnn, const float* __restrict__ Wno,
    ushort* __restrict__ whi, ushort* __restrict__ wlo)
{
    size_t idx4 = (size_t)(blockIdx.x * 256 + threadIdx.x) * 4;   // over 2*2^23
    int mat = (int)(idx4 >> 23);
    size_t rem = idx4 & 8388607u;
    int j = (int)(rem >> 10), k = (int)(rem & 1023);
    const float* W = mat ? Wno : Wnn;
    float4 v = *(const float4*)&W[(size_t)j * KF + k];
    ushort4 a, b;
    a.x = f2bf(v.x); b.x = f2bf(v.x - bf2f(a.x));
    a.y = f2bf(v.y); b.y = f2bf(v.y - bf2f(a.y));
    a.z = f2bf(v.z); b.z = f2bf(v.z - bf2f(a.z));
    a.w = f2bf(v.w); b.w = f2bf(v.w - bf2f(a.w));
    *(ushort4*)&whi[idx4] = a;
    *(ushort4*)&wlo[idx4] = b;
}

// ---- prep: W_E (k<1024) -> bf16 hi, layout [j][k] ----
__global__ __launch_bounds__(256) void k_prep_we(
    const float* __restrict__ WE, ushort* __restrict__ weh)
{
    size_t idx4 = (size_t)(blockIdx.x * 256 + threadIdx.x) * 4;   // over 2^23
    int j = (int)(idx4 >> 10), k = (int)(idx4 & 1023);
    float4 v = *(const float4*)&WE[(size_t)j * KF + k];
    ushort4 a;
    a.x = f2bf(v.x); a.y = f2bf(v.y); a.z = f2bf(v.z); a.w = f2bf(v.w);
    *(ushort4*)&weh[idx4] = a;
}

// ---- m-bias: Bc[mat*NJ+j] = f64(R . W[1024:1536)) + b ----
__global__ __launch_bounds__(256) void k_bc(
    const float* __restrict__ R32, const float* __restrict__ Wnn, const float* __restrict__ Wno,
    const float* __restrict__ bnn, const float* __restrict__ bno, float* __restrict__ Bc)
{
    int idx = blockIdx.x * 256 + threadIdx.x;
    int mat = idx >> 13, j = idx & 8191;
    const float* W = mat ? Wno : Wnn;
    const float* b = mat ? bno : bnn;
    double acc = 0.0;
    for (int k = 1024; k < 1536; ++k)
        acc += (double)R32[k - KU] * (double)W[(size_t)j * KF + k];
    Bc[idx] = (float)(acc + (double)b[j]);
}

// ---- e-bias: Bce[j] = f64(R . WE[1024:1536)) + bE ----
__global__ __launch_bounds__(256) void k_bce(
    const float* __restrict__ R32, const float* __restrict__ WE,
    const float* __restrict__ bE, float* __restrict__ Bce)
{
    int j = blockIdx.x * 256 + threadIdx.x;
    double acc = 0.0;
    for (int k = 1024; k < 1536; ++k)
        acc += (double)R32[k - KU] * (double)WE[(size_t)j * KF + k];
    Bce[j] = (float)(acc + (double)bE[j]);
}

__global__ void k_zero(int* __restrict__ cnt) { *cnt = 0; }

// ---- fused m+e kernel: 7 MFMA passes (3 per m-mat + 1 e) + gate ----
union MSm {
    struct {
        ushort u1[4096], u2[4096];   // 128 rows x 32 k, swizzled
        ushort w1[4096], w2[4096];   // [mat(2)][64 rows][32 k], swizzled
        ushort we[2048];             // 64 rows x 32 k, swizzled
    } st;                            // 36864 B
    struct {
        float  m[128][66];
        ushort e[128][66];
    } ep;                            // 50688 B
};

__global__ __launch_bounds__(256, 3) void k_m(
    const ushort* __restrict__ uhi, const ushort* __restrict__ ulo,
    const ushort* __restrict__ whi, const ushort* __restrict__ wlo,
    const ushort* __restrict__ weh,
    const float* __restrict__ noise,
    const float* __restrict__ Bc, const float* __restrict__ Bce,
    int* __restrict__ cnt, int* __restrict__ wl, float* __restrict__ out)
{
    __shared__ MSm sm;
    const int tid = threadIdx.x;
    const int w = tid >> 6, l = tid & 63;
    const int wm = w >> 1, wn = w & 1;
    const int lr = l & 15, lq = l >> 4;
    const int sBase = blockIdx.y * 128;
    const int jBase = blockIdx.x * 64;
    const int dBase = jBase >> 4;

    f32x4 acc1[4][2] = {}, acc2[4][2] = {}, accE[4][2] = {};

    for (int kt = 0; kt < KU; kt += BK) {
        __syncthreads();
        #pragma unroll
        for (int it = 0; it < 2; ++it) {
            int c = tid + it * 256;                 // 512 chunks: u tile
            int row = c >> 2, c16 = c & 3;
            int ds = swzi(row, c16);
            size_t go = (size_t)(sBase + row) * KU + kt + c16 * 8;
            *(uint4*)&sm.st.u1[ds] = *(const uint4*)&uhi[go];
            *(uint4*)&sm.st.u2[ds] = *(const uint4*)&ulo[go];
        }
        #pragma unroll
        for (int it = 0; it < 2; ++it) {
            int c = tid + it * 256;                 // 512 chunks: w tiles
            int mat = c >> 8, col = (c >> 2) & 63, c16 = c & 3;
            int ds = mat * 2048 + swzi(col, c16);
            size_t go = ((size_t)mat * NJ + jBase + col) * KU + kt + c16 * 8;
            *(uint4*)&sm.st.w1[ds] = *(const uint4*)&whi[go];
            *(uint4*)&sm.st.w2[ds] = *(const uint4*)&wlo[go];
        }
        {
            int col = tid >> 2, c16 = tid & 3;      // 256 chunks: we tile
            int ds = swzi(col, c16);
            size_t go = (size_t)(jBase + col) * KU + kt + c16 * 8;
            *(uint4*)&sm.st.we[ds] = *(const uint4*)&weh[go];
        }
        __syncthreads();
        bf16x8 a1[4], a2[4];
        #pragma unroll
        for (int i = 0; i < 4; ++i) {
            int ds = swzi(wm * 64 + i * 16 + lr, lq);
            a1[i] = *(const bf16x8*)&sm.st.u1[ds];
            a2[i] = *(const bf16x8*)&sm.st.u2[ds];
        }
        #pragma unroll
        for (int n = 0; n < 2; ++n) {
            int dsn = swzi(wn * 32 + n * 16 + lr, lq);
            bf16x8 p10 = *(const bf16x8*)&sm.st.w1[dsn];
            bf16x8 p20 = *(const bf16x8*)&sm.st.w2[dsn];
            bf16x8 p11 = *(const bf16x8*)&sm.st.w1[2048 + dsn];
            bf16x8 p21 = *(const bf16x8*)&sm.st.w2[2048 + dsn];
            bf16x8 pe  = *(const bf16x8*)&sm.st.we[dsn];
            #pragma unroll
            for (int i = 0; i < 4; ++i) {
                acc1[i][n] = __builtin_amdgcn_mfma_f32_16x16x32_bf16(a1[i], p10, acc1[i][n], 0, 0, 0);
                acc1[i][n] = __builtin_amdgcn_mfma_f32_16x16x32_bf16(a1[i], p20, acc1[i][n], 0, 0, 0);
                acc1[i][n] = __builtin_amdgcn_mfma_f32_16x16x32_bf16(a2[i], p10, acc1[i][n], 0, 0, 0);
                acc2[i][n] = __builtin_amdgcn_mfma_f32_16x16x32_bf16(a1[i], p11, acc2[i][n], 0, 0, 0);
                acc2[i][n] = __builtin_amdgcn_mfma_f32_16x16x32_bf16(a1[i], p21, acc2[i][n], 0, 0, 0);
                acc2[i][n] = __builtin_amdgcn_mfma_f32_16x16x32_bf16(a2[i], p11, acc2[i][n], 0, 0, 0);
                accE[i][n] = __builtin_amdgcn_mfma_f32_16x16x32_bf16(a1[i], pe,  accE[i][n], 0, 0, 0);
            }
        }
    }

    __syncthreads();
    float bc1[2], bc2[2], be[2];
    #pragma unroll
    for (int n = 0; n < 2; ++n) {
        int col = jBase + wn * 32 + n * 16 + lr;
        bc1[n] = Bc[col];
        bc2[n] = Bc[NJ + col];
        be[n]  = Bce[col];
    }
    #pragma unroll
    for (int i = 0; i < 4; ++i)
        #pragma unroll
        for (int n = 0; n < 2; ++n) {
            int colL = wn * 32 + n * 16 + lr;
            #pragma unroll
            for (int r = 0; r < 4; ++r) {
                int rowL = wm * 64 + i * 16 + (lq << 2) + r;
                float m1 = acc1[i][n][r] + bc1[n];
                float m2 = acc2[i][n][r] + bc2[n];
                float nz = noise[(size_t)(sBase + rowL) * NJ + jBase + colL];
                sm.ep.m[rowL][colL] = fmaf(m2, nz, m1);
                sm.ep.e[rowL][colL] = f2bf(accE[i][n][r] + be[n]);
            }
        }
    __syncthreads();

    for (int site = tid; site < 512; site += 256) {
        int srow = site >> 2, dl = site & 3;
        float v1 = -INFINITY, v2 = -INFINITY, v3 = -INFINITY;
        float ev1 = 0.f, ev2 = 0.f;
        #pragma unroll
        for (int e = 0; e < 16; ++e) {
            float m = sm.ep.m[srow][dl * 16 + e];
            float ev = bf2f(sm.ep.e[srow][dl * 16 + e]);
            if (m > v1)      { v3 = v2; v2 = v1; ev2 = ev1; v1 = m; ev1 = ev; }
            else if (m > v2) { v3 = v2; v2 = m; ev2 = ev; }
            else if (m > v3) { v3 = m; }
        }
        int gidx = (sBase + srow) * DIMD + dBase + dl;
        bool flg = (v2 - v3 < GAP_T) || (fabsf(v1) < GAP_T) || (fabsf(v2) < GAP_T);
        if (flg) {
            int pos = atomicAdd(cnt, 1);
            wl[pos] = gidx;
        }
        double x1 = (double)v1, x2 = (double)v2;
        double vmax = fmax(x1, x2);
        double g1 = exp(x1 - vmax), g2 = exp(x2 - vmax);
        double num = g1 * (double)ev1 + g2 * (double)ev2;
        out[gidx] = (float)(num / (g1 + g2) * 0.0625);
    }
}

// ---- repair: one wave per flagged site; lane = (expert, mat) exact chain ----
__global__ __launch_bounds__(256) void k_repair(
    const float* __restrict__ u, const float* __restrict__ noise,
    const float* __restrict__ Wnn, const float* __restrict__ Wno, const float* __restrict__ WE,
    const float* __restrict__ bnn, const float* __restrict__ bno, const float* __restrict__ bE,
    const float* __restrict__ R32,
    const int* __restrict__ cnt, const int* __restrict__ wl, float* __restrict__ out)
{
    const int l = threadIdx.x & 63;
    const int e = l & 15, mt = l >> 4;          // mt in 0..3 (3 idle)
    const int wid = (blockIdx.x * 256 + threadIdx.x) >> 6;
    const int NW = (512 * 256) >> 6;
    const int n = *cnt;

    for (int i = wid; i < n; i += NW) {
        int si = wl[i];
        int s = si >> 9, d = si & 511;
        int j = d * 16 + e;
        const float* urow = u + (size_t)s * KU;
        float t = 0.f;
        if (mt < 3) {
            const float* Wrow = (mt == 0 ? Wnn : (mt == 1 ? Wno : WE)) + (size_t)j * KF;
            #pragma unroll
            for (int c = 0; c < 4; ++c) {
                float cc = 0.f;
                int k0 = c * KC;
                for (int k = k0; k < k0 + KC; ++k) {
                    float a = (k < KU) ? urow[k] : R32[k - KU];
                    cc = fmaf(a, Wrow[k], cc);
                }
                t = __fadd_rn(t, cc);
            }
            t = __fadd_rn(t, (mt == 0 ? bnn : (mt == 1 ? bno : bE))[j]);
        }
        float h2 = __shfl(t, 16 + e);
        float ee = __shfl(t, 32 + e);
        float m = -INFINITY;
        if (mt == 0)
            m = __fadd_rn(t, __fmul_rn(h2, noise[(size_t)s * NJ + j]));
        // index-stable top-1 over lanes 0..15 (xor masks stay in-group)
        float v1 = m; int i1 = e;
        #pragma unroll
        for (int mk = 1; mk <= 8; mk <<= 1) {
            float ov = __shfl_xor(v1, mk);
            int oi = __shfl_xor(i1, mk);
            if (ov > v1 || (ov == v1 && oi < i1)) { v1 = ov; i1 = oi; }
        }
        float v2 = (mt == 0 && e == i1) ? -INFINITY : m;
        int i2 = (mt == 0 && e == i1) ? 64 : e;
        #pragma unroll
        for (int mk = 1; mk <= 8; mk <<= 1) {
            float ov = __shfl_xor(v2, mk);
            int oi = __shfl_xor(i2, mk);
            if (ov > v2 || (ov == v2 && oi < i2)) { v2 = ov; i2 = oi; }
        }
        float se = ee;
        #pragma unroll
        for (int mk = 1; mk <= 8; mk <<= 1) se += __shfl_xor(se, mk);
        float ev1 = __shfl(ee, i1);
        float ev2 = __shfl(ee, i2 & 15);
        if (l == 0) {
            double x1 = (v1 == 0.0f) ? -100000.0 : (double)v1;
            double x2 = (v2 == 0.0f) ? -100000.0 : (double)v2;
            double vmax = fmax(fmax(x1, x2), -100000.0);
            double g1 = exp(x1 - vmax), g2 = exp(x2 - vmax), gz = exp(-100000.0 - vmax);
            double den = g1 + g2 + 14.0 * gz;
            double num = g1 * (double)ev1 + g2 * (double)ev2
                       + gz * ((double)se - (double)ev1 - (double)ev2);
            out[si] = (float)(num / den * 0.0625);
        }
    }
}

// ---- fallback: proven round-5 ws-free kernel (bit-identical arithmetic) ----
__global__ __launch_bounds__(256) void k_base(
    const float* __restrict__ u, const float* __restrict__ noise,
    const float* __restrict__ Wnn, const float* __restrict__ Wno, const float* __restrict__ WE,
    const float* __restrict__ bnn, const float* __restrict__ bno, const float* __restrict__ bE,
    const float* __restrict__ h, const float* __restrict__ us, const float* __restrict__ ue,
    const float* __restrict__ Wr, const float* __restrict__ br,
    float* __restrict__ out)
{
    __shared__ __align__(16) float As[BM][PA];
    __shared__ __align__(16) float Ws[3][BK][PW];
    __shared__ float Rsh[512];

    const int tid = threadIdx.x;
    const int sr = tid >> 2, dl = tid & 3;
    const int jBase = blockIdx.x * 64;
    const int sBase = blockIdx.y * BM;
    const int myCol = dl * 16;

    for (int o = tid; o < 512; o += 256) Rsh[o] = chainR(h, us, ue, Wr, br, o);

    float t1[16] = {}, c1[16] = {}, t2[16] = {}, c2[16] = {}, tE[16] = {}, cE[16] = {};

    for (int kt = 0; kt < KF; kt += BK) {
        __syncthreads();
        if (kt < KU) {
            for (int idx = tid; idx < BM * BK; idx += 256) {
                int r = idx >> 5, c = idx & 31;
                As[r][c] = u[(size_t)(sBase + r) * KU + kt + c];
            }
        }
        for (int idx = tid; idx < 64 * BK; idx += 256) {
            int col = idx >> 5, kk = idx & 31;
            size_t off = (size_t)(jBase + col) * KF + kt + kk;
            Ws[0][kk][col] = Wnn[off];
            Ws[1][kk][col] = Wno[off];
            Ws[2][kk][col] = WE[off];
        }
        __syncthreads();
        const bool uReg = (kt < KU);
        for (int kk = 0; kk < BK; ++kk) {
            float a = uReg ? As[sr][kk] : Rsh[kt + kk - KU];
            #pragma unroll
            for (int q = 0; q < 4; ++q) {
                float4 w0 = *(const float4*)&Ws[0][kk][myCol + 4 * q];
                float4 w1 = *(const float4*)&Ws[1][kk][myCol + 4 * q];
                float4 w2 = *(const float4*)&Ws[2][kk][myCol + 4 * q];
                c1[4*q+0] = fmaf(a, w0.x, c1[4*q+0]);
                c1[4*q+1] = fmaf(a, w0.y, c1[4*q+1]);
                c1[4*q+2] = fmaf(a, w0.z, c1[4*q+2]);
                c1[4*q+3] = fmaf(a, w0.w, c1[4*q+3]);
                c2[4*q+0] = fmaf(a, w1.x, c2[4*q+0]);
                c2[4*q+1] = fmaf(a, w1.y, c2[4*q+1]);
                c2[4*q+2] = fmaf(a, w1.z, c2[4*q+2]);
                c2[4*q+3] = fmaf(a, w1.w, c2[4*q+3]);
                cE[4*q+0] = fmaf(a, w2.x, cE[4*q+0]);
                cE[4*q+1] = fmaf(a, w2.y, cE[4*q+1]);
                cE[4*q+2] = fmaf(a, w2.z, cE[4*q+2]);
                cE[4*q+3] = fmaf(a, w2.w, cE[4*q+3]);
            }
        }
        if (((kt + BK) % KC) == 0 || (kt + BK) == KF) {
            #pragma unroll
            for (int e = 0; e < 16; ++e) {
                t1[e] = __fadd_rn(t1[e], c1[e]); c1[e] = 0.f;
                t2[e] = __fadd_rn(t2[e], c2[e]); c2[e] = 0.f;
                tE[e] = __fadd_rn(tE[e], cE[e]); cE[e] = 0.f;
            }
        }
    }

    const int s = sBase + sr;
    const int jb = jBase + myCol;
    float m32[16]; double evv[16];
    #pragma unroll
    for (int e = 0; e < 16; ++e) {
        float h1 = __fadd_rn(t1[e], bnn[jb + e]);
        float h2 = __fadd_rn(t2[e], bno[jb + e]);
        float nz = noise[(size_t)s * NJ + jb + e];
        m32[e] = __fadd_rn(h1, __fmul_rn(h2, nz));
        evv[e] = (double)__fadd_rn(tE[e], bE[jb + e]);
    }
    int i1 = 0; float v1 = m32[0];
    #pragma unroll
    for (int e = 1; e < 16; ++e) if (m32[e] > v1) { v1 = m32[e]; i1 = e; }
    int i2 = -1; float v2 = -INFINITY;
    #pragma unroll
    for (int e = 0; e < 16; ++e) if (e != i1 && m32[e] > v2) { v2 = m32[e]; i2 = e; }
    double e1 = 0.0, e2 = 0.0, sumE = 0.0;
    #pragma unroll
    for (int e = 0; e < 16; ++e) {
        e1 = (e == i1) ? evv[e] : e1;
        e2 = (e == i2) ? evv[e] : e2;
        sumE += evv[e];
    }
    double x1 = (v1 == 0.0f) ? -100000.0 : (double)v1;
    double x2 = (v2 == 0.0f) ? -100000.0 : (double)v2;
    double vmax = fmax(fmax(x1, x2), -100000.0);
    double g1 = exp(x1 - vmax), g2 = exp(x2 - vmax), gz = exp(-100000.0 - vmax);
    double den = g1 + g2 + 14.0 * gz;
    double num = g1 * e1 + g2 * e2 + gz * (sumE - e1 - e2);
    out[(size_t)s * DIMD + (jBase >> 4) + dl] = (float)(num / den * 0.0625);
}

extern "C" void kernel_launch(void* const* d_in, const int* in_sizes, int n_in,
                              void* d_out, int out_size, void* d_ws, size_t ws_size,
                              hipStream_t stream) {
    (void)in_sizes; (void)n_in; (void)out_size;
    const float* h     = (const float*)d_in[0];
    const float* us    = (const float*)d_in[1];
    const float* ue    = (const float*)d_in[2];
    const float* u     = (const float*)d_in[3];
    const float* noise = (const float*)d_in[4];
    const float* Wnn   = (const float*)d_in[5];
    const float* bnn   = (const float*)d_in[6];
    const float* Wno   = (const float*)d_in[7];
    const float* bno   = (const float*)d_in[8];
    const float* WE    = (const float*)d_in[9];
    const float* bE    = (const float*)d_in[10];
    const float* Wr    = (const float*)d_in[11];
    const float* br    = (const float*)d_in[12];
    float* out = (float*)d_out;

    if (ws_size >= WS_NEEDED) {
        char* ws = (char*)d_ws;
        float* Rws  = (float*)(ws + WS_R);
        float* Bc   = (float*)(ws + WS_BC);
        float* Bce  = (float*)(ws + WS_BCE);
        int*   cnt  = (int*)(ws + WS_CNT);
        int*   wl   = (int*)(ws + WS_WL);
        ushort* uhi = (ushort*)(ws + WS_UHI);
        ushort* ulo = (ushort*)(ws + WS_ULO);
        ushort* whi = (ushort*)(ws + WS_WHI);
        ushort* wlo = (ushort*)(ws + WS_WLO);
        ushort* weh = (ushort*)(ws + WS_WEH);

        hipLaunchKernelGGL(k_R32, dim3(2), dim3(256), 0, stream, h, us, ue, Wr, br, Rws);
        hipLaunchKernelGGL(k_prep_u, dim3(SEQL * KU / 1024), dim3(256), 0, stream, u, uhi, ulo);
        hipLaunchKernelGGL(k_prep_w, dim3(2 * NJ * KU / 1024), dim3(256), 0, stream, Wnn, Wno, whi, wlo);
        hipLaunchKernelGGL(k_prep_we, dim3(NJ * KU / 1024), dim3(256), 0, stream, WE, weh);
        hipLaunchKernelGGL(k_bc, dim3(64), dim3(256), 0, stream, Rws, Wnn, Wno, bnn, bno, Bc);
        hipLaunchKernelGGL(k_bce, dim3(32), dim3(256), 0, stream, Rws, WE, bE, Bce);
        hipLaunchKernelGGL(k_zero, dim3(1), dim3(1), 0, stream, cnt);
        hipLaunchKernelGGL(k_m, dim3(NJ / 64, SEQL / 128), dim3(256), 0, stream,
                           uhi, ulo, whi, wlo, weh, noise, Bc, Bce, cnt, wl, out);
        hipLaunchKernelGGL(k_repair, dim3(512), dim3(256), 0, stream,
                           u, noise, Wnn, Wno, WE, bnn, bno, bE, Rws, cnt, wl, out);
    } else {
        hipLaunchKernelGGL(k_base, dim3(NJ / 64, SEQL / BM), dim3(256), 0, stream,
                           u, noise, Wnn, Wno, WE, bnn, bno, bE,
                           h, us, ue, Wr, br, out);
    }
}

// Round 10
// 1475.964 us; speedup vs baseline: 1.4477x; 1.4477x over previous
//
#include <hip/hip_runtime.h>
#include <hip/hip_bf16.h>
#include <math.h>

#define DIMD 512
#define SEQL 4096
#define KU 1024
#define KF 1536
#define NJ 8192
#define KC 384          // OpenBLAS sgemm K-blocking (matched in round 5)
#define NTK 32          // KU/32 k-tiles

#define BM 64
#define BK 32
#define PA 33
#define PW 68

#define GAP_T 1e-3f

// ---- ws layout (bytes) ----
#define WS_R    0u          // 512 f32
#define WS_BC   4096u       // 2*8192 f32 (m-path combined bias, f64-folded)
#define WS_BCE  69632u      // 8192 f32 (e-path combined bias, f64-folded)
#define WS_CNT  102400u     // int counter
#define WS_WL   102656u     // worklist (2.1M ints max)
#define WS_UHI  8491264u    // 4096*1024 bf16, fragment order
#define WS_ULO  16879872u   // 4096*1024 bf16, fragment order
#define WS_WHI  25268480u   // 2*8192*1024 bf16 (Wnn,Wno hi), fragment order
#define WS_WLO  58822912u   // 2*8192*1024 bf16 (lo), fragment order
#define WS_WEH  92377344u   // 8192*1024 bf16 (W_E hi), fragment order
#define WS_NEEDED 109154560u

typedef __attribute__((ext_vector_type(8))) short bf16x8;
typedef __attribute__((ext_vector_type(4))) float f32x4;

__device__ __forceinline__ ushort f2bf(float f) {
    __hip_bfloat16 h = __float2bfloat16(f);
    return *reinterpret_cast<ushort*>(&h);
}
__device__ __forceinline__ float bf2f(ushort v) {
    unsigned int b = ((unsigned int)v) << 16;
    return __uint_as_float(b);
}

// ---- f32 R with the exact chunked fma chain (k-ascending, KC blocks) ----
__device__ __forceinline__ float chainR(
    const float* __restrict__ h, const float* __restrict__ us, const float* __restrict__ ue,
    const float* __restrict__ Wr, const float* __restrict__ br, int o)
{
    float accT = 0.f;
    for (int k0 = 0; k0 < 2560; k0 += KC) {
        int ke = (k0 + KC < 2560) ? k0 + KC : 2560;
        float accC = 0.f;
        for (int k = k0; k < ke; ++k) {
            float xv = (k < 1536) ? h[k] : (k < 2048) ? us[k - 1536] : ue[k - 2048];
            accC = fmaf(xv, Wr[(size_t)o * 2560 + k], accC);
        }
        accT = __fadd_rn(accT, accC);
    }
    return __fadd_rn(accT, br[o]);
}

__global__ __launch_bounds__(256) void k_R32(
    const float* __restrict__ h, const float* __restrict__ us, const float* __restrict__ ue,
    const float* __restrict__ Wr, const float* __restrict__ br, float* __restrict__ Rout)
{
    int o = blockIdx.x * 256 + threadIdx.x;
    Rout[o] = chainR(h, us, ue, Wr, br, o);
}

// ---- prep: u -> bf16 hi/lo in MFMA A-fragment order ----
// frag chunk c = ((s16*NTK + k32)*64 + l); element j from u[s16*16+(l&15)][k32*32+(l>>4)*8+j]
__global__ __launch_bounds__(256) void k_prep_u(
    const float* __restrict__ u, ushort* __restrict__ uhi, ushort* __restrict__ ulo)
{
    int c = blockIdx.x * 256 + threadIdx.x;          // 0 .. SEQL*KU/8-1
    int l = c & 63, t = c >> 6;
    int k32 = t & (NTK - 1), s16 = t >> 5;
    int row = s16 * 16 + (l & 15);
    int k0 = k32 * 32 + (l >> 4) * 8;
    const float* src = &u[(size_t)row * KU + k0];
    ushort a[8], b[8];
    #pragma unroll
    for (int j = 0; j < 8; ++j) {
        float v = src[j];
        a[j] = f2bf(v);
        b[j] = f2bf(v - bf2f(a[j]));
    }
    *(uint4*)&uhi[(size_t)c * 8] = *(uint4*)a;
    *(uint4*)&ulo[(size_t)c * 8] = *(uint4*)b;
}

// ---- prep: Wnn/Wno (k<1024) -> bf16 hi/lo, B-fragment order ----
__global__ __launch_bounds__(256) void k_prep_w(
    const float* __restrict__ Wnn, const float* __restrict__ Wno,
    ushort* __restrict__ whi, ushort* __restrict__ wlo)
{
    int c = blockIdx.x * 256 + threadIdx.x;          // 0 .. 2*NJ*KU/8-1
    int l = c & 63, t = c >> 6;
    int k32 = t & (NTK - 1), j16 = (t >> 5) & 511, mat = t >> 14;
    int col = j16 * 16 + (l & 15);
    int k0 = k32 * 32 + (l >> 4) * 8;
    const float* W = mat ? Wno : Wnn;
    const float* src = &W[(size_t)col * KF + k0];
    ushort a[8], b[8];
    #pragma unroll
    for (int j = 0; j < 8; ++j) {
        float v = src[j];
        a[j] = f2bf(v);
        b[j] = f2bf(v - bf2f(a[j]));
    }
    *(uint4*)&whi[(size_t)c * 8] = *(uint4*)a;
    *(uint4*)&wlo[(size_t)c * 8] = *(uint4*)b;
}

// ---- prep: W_E (k<1024) -> bf16 hi, B-fragment order ----
__global__ __launch_bounds__(256) void k_prep_we(
    const float* __restrict__ WE, ushort* __restrict__ weh)
{
    int c = blockIdx.x * 256 + threadIdx.x;          // 0 .. NJ*KU/8-1
    int l = c & 63, t = c >> 6;
    int k32 = t & (NTK - 1), j16 = t >> 5;
    int col = j16 * 16 + (l & 15);
    int k0 = k32 * 32 + (l >> 4) * 8;
    const float* src = &WE[(size_t)col * KF + k0];
    ushort a[8];
    #pragma unroll
    for (int j = 0; j < 8; ++j) a[j] = f2bf(src[j]);
    *(uint4*)&weh[(size_t)c * 8] = *(uint4*)a;
}

// ---- m-bias: Bc[mat*NJ+j] = f64(R . W[1024:1536)) + b  (wave per output) ----
__global__ __launch_bounds__(256) void k_bc(
    const float* __restrict__ R32, const float* __restrict__ Wnn, const float* __restrict__ Wno,
    const float* __restrict__ bnn, const float* __restrict__ bno, float* __restrict__ Bc)
{
    int wid = blockIdx.x * 4 + (threadIdx.x >> 6);   // 0..16383
    int l = threadIdx.x & 63;
    int mat = wid >> 13, j = wid & 8191;
    const float* W = mat ? Wno : Wnn;
    const float* b = mat ? bno : bnn;
    double acc = 0.0;
    for (int k = 1024 + l; k < 1536; k += 64)
        acc += (double)R32[k - KU] * (double)W[(size_t)j * KF + k];
    for (int off = 32; off > 0; off >>= 1) acc += __shfl_down(acc, off);
    if (l == 0) Bc[wid] = (float)(acc + (double)b[j]);
}

// ---- e-bias: Bce[j] = f64(R . WE[1024:1536)) + bE  (wave per output) ----
__global__ __launch_bounds__(256) void k_bce(
    const float* __restrict__ R32, const float* __restrict__ WE,
    const float* __restrict__ bE, float* __restrict__ Bce)
{
    int j = blockIdx.x * 4 + (threadIdx.x >> 6);     // 0..8191
    int l = threadIdx.x & 63;
    double acc = 0.0;
    for (int k = 1024 + l; k < 1536; k += 64)
        acc += (double)R32[k - KU] * (double)WE[(size_t)j * KF + k];
    for (int off = 32; off > 0; off >>= 1) acc += __shfl_down(acc, off);
    if (l == 0) Bce[j] = (float)(acc + (double)bE[j]);
}

__global__ void k_zero(int* __restrict__ cnt) { *cnt = 0; }

// ---- fused m+e kernel: linear fragment LDS, 7 MFMA passes, odd-stride gate ----
union MSm {
    struct {
        ushort u1[4096], u2[4096];    // 8 s16-tiles x 64 lanes x 8
        ushort w1[4096], w2[4096];    // (2 mats x 4 j16-tiles) x 64 x 8
        ushort we[2048];              // 4 j16-tiles x 64 x 8
    } st;                             // 36864 B
    struct {
        float m[512 * 17];            // [site][17] odd stride
        float e[512 * 17];
    } ep;                             // 69632 B
};

__global__ __launch_bounds__(256, 2) void k_m(
    const ushort* __restrict__ uhi, const ushort* __restrict__ ulo,
    const ushort* __restrict__ whi, const ushort* __restrict__ wlo,
    const ushort* __restrict__ weh,
    const float* __restrict__ noise,
    const float* __restrict__ Bc, const float* __restrict__ Bce,
    int* __restrict__ cnt, int* __restrict__ wl, float* __restrict__ out)
{
    __shared__ MSm sm;
    const int tid = threadIdx.x;
    const int w = tid >> 6, l = tid & 63;
    const int wm = w >> 1, wn = w & 1;
    const int lr = l & 15, lq = l >> 4;
    const int l8 = l * 8;
    const int sBase = blockIdx.y * 128;
    const int sB16 = blockIdx.y * 8;
    const int jBase = blockIdx.x * 64;
    const int jB16 = blockIdx.x * 4;
    const int dBase = jBase >> 4;

    f32x4 acc1[4][2] = {}, acc2[4][2] = {}, accE[4][2] = {};

    for (int kt = 0; kt < NTK; ++kt) {
        __syncthreads();
        #pragma unroll
        for (int it = 0; it < 4; ++it) {            // u: 1024 x 16B
            int c = tid + it * 256;
            int buf = c >> 9, rem = c & 511;        // rem = ts*64 + lane
            size_t g = (((size_t)(sB16 + (rem >> 6)) * NTK + kt) * 64 + (rem & 63)) * 8;
            const ushort* src = buf ? ulo : uhi;
            ushort* dst = (buf ? sm.st.u2 : sm.st.u1) + rem * 8;
            *(uint4*)dst = *(const uint4*)&src[g];
        }
        #pragma unroll
        for (int it = 0; it < 4; ++it) {            // w: 1024 x 16B
            int c = tid + it * 256;
            int buf = c >> 9, rem = c & 511;        // rem = (mt*4+jt)*64 + lane
            int mt = rem >> 8, jt = (rem >> 6) & 3;
            size_t g = ((((size_t)mt * 512 + jB16 + jt) * NTK + kt) * 64 + (rem & 63)) * 8;
            const ushort* src = buf ? wlo : whi;
            ushort* dst = (buf ? sm.st.w2 : sm.st.w1) + rem * 8;
            *(uint4*)dst = *(const uint4*)&src[g];
        }
        {                                           // we: 256 x 16B
            int jt = tid >> 6;
            size_t g = (((size_t)(jB16 + jt) * NTK + kt) * 64 + (tid & 63)) * 8;
            *(uint4*)&sm.st.we[tid * 8] = *(const uint4*)&weh[g];
        }
        __syncthreads();
        bf16x8 a1[4], a2[4];
        #pragma unroll
        for (int i = 0; i < 4; ++i) {
            int base = (wm * 4 + i) * 512 + l8;
            a1[i] = *(const bf16x8*)&sm.st.u1[base];
            a2[i] = *(const bf16x8*)&sm.st.u2[base];
        }
        #pragma unroll
        for (int n = 0; n < 2; ++n) {
            int jloc = wn * 2 + n;
            bf16x8 p10 = *(const bf16x8*)&sm.st.w1[jloc * 512 + l8];
            bf16x8 p20 = *(const bf16x8*)&sm.st.w2[jloc * 512 + l8];
            bf16x8 p11 = *(const bf16x8*)&sm.st.w1[(4 + jloc) * 512 + l8];
            bf16x8 p21 = *(const bf16x8*)&sm.st.w2[(4 + jloc) * 512 + l8];
            bf16x8 pe  = *(const bf16x8*)&sm.st.we[jloc * 512 + l8];
            #pragma unroll
            for (int i = 0; i < 4; ++i) {
                acc1[i][n] = __builtin_amdgcn_mfma_f32_16x16x32_bf16(a1[i], p10, acc1[i][n], 0, 0, 0);
                acc1[i][n] = __builtin_amdgcn_mfma_f32_16x16x32_bf16(a1[i], p20, acc1[i][n], 0, 0, 0);
                acc1[i][n] = __builtin_amdgcn_mfma_f32_16x16x32_bf16(a2[i], p10, acc1[i][n], 0, 0, 0);
                acc2[i][n] = __builtin_amdgcn_mfma_f32_16x16x32_bf16(a1[i], p11, acc2[i][n], 0, 0, 0);
                acc2[i][n] = __builtin_amdgcn_mfma_f32_16x16x32_bf16(a1[i], p21, acc2[i][n], 0, 0, 0);
                acc2[i][n] = __builtin_amdgcn_mfma_f32_16x16x32_bf16(a2[i], p11, acc2[i][n], 0, 0, 0);
                accE[i][n] = __builtin_amdgcn_mfma_f32_16x16x32_bf16(a1[i], pe,  accE[i][n], 0, 0, 0);
            }
        }
    }

    __syncthreads();
    float bc1[2], bc2[2], be[2];
    #pragma unroll
    for (int n = 0; n < 2; ++n) {
        int col = jBase + wn * 32 + n * 16 + lr;
        bc1[n] = Bc[col];
        bc2[n] = Bc[NJ + col];
        be[n]  = Bce[col];
    }
    #pragma unroll
    for (int i = 0; i < 4; ++i)
        #pragma unroll
        for (int n = 0; n < 2; ++n) {
            int colL = wn * 32 + n * 16 + lr;
            int dloc = wn * 2 + n;
            #pragma unroll
            for (int r = 0; r < 4; ++r) {
                int rowL = wm * 64 + i * 16 + lq * 4 + r;
                float m1 = acc1[i][n][r] + bc1[n];
                float m2 = acc2[i][n][r] + bc2[n];
                float nz = noise[(size_t)(sBase + rowL) * NJ + jBase + colL];
                int site = rowL * 4 + dloc;
                sm.ep.m[site * 17 + lr] = fmaf(m2, nz, m1);
                sm.ep.e[site * 17 + lr] = accE[i][n][r] + be[n];
            }
        }
    __syncthreads();

    for (int s2 = tid; s2 < 512; s2 += 256) {
        float v1 = -INFINITY, v2 = -INFINITY, v3 = -INFINITY;
        float ev1 = 0.f, ev2 = 0.f;
        #pragma unroll
        for (int e = 0; e < 16; ++e) {
            float m = sm.ep.m[s2 * 17 + e];
            float ev = sm.ep.e[s2 * 17 + e];
            if (m > v1)      { v3 = v2; v2 = v1; ev2 = ev1; v1 = m; ev1 = ev; }
            else if (m > v2) { v3 = v2; v2 = m; ev2 = ev; }
            else if (m > v3) { v3 = m; }
        }
        int gidx = (sBase + (s2 >> 2)) * DIMD + dBase + (s2 & 3);
        bool flg = (v2 - v3 < GAP_T) || (fabsf(v1) < GAP_T) || (fabsf(v2) < GAP_T);
        if (flg) {
            int pos = atomicAdd(cnt, 1);
            wl[pos] = gidx;
        }
        double x1 = (double)v1, x2 = (double)v2;
        double vmax = fmax(x1, x2);
        double g1 = exp(x1 - vmax), g2 = exp(x2 - vmax);
        double num = g1 * (double)ev1 + g2 * (double)ev2;
        out[gidx] = (float)(num / (g1 + g2) * 0.0625);
    }
}

// ---- repair: one wave per flagged site; lane = (expert, mat) exact chain ----
__global__ __launch_bounds__(256) void k_repair(
    const float* __restrict__ u, const float* __restrict__ noise,
    const float* __restrict__ Wnn, const float* __restrict__ Wno, const float* __restrict__ WE,
    const float* __restrict__ bnn, const float* __restrict__ bno, const float* __restrict__ bE,
    const float* __restrict__ R32,
    const int* __restrict__ cnt, const int* __restrict__ wl, float* __restrict__ out)
{
    const int l = threadIdx.x & 63;
    const int e = l & 15, mt = l >> 4;          // mt in 0..3 (3 idle)
    const int wid = (blockIdx.x * 256 + threadIdx.x) >> 6;
    const int NW = (512 * 256) >> 6;
    const int n = *cnt;

    for (int i = wid; i < n; i += NW) {
        int si = wl[i];
        int s = si >> 9, d = si & 511;
        int j = d * 16 + e;
        const float* urow = u + (size_t)s * KU;
        float t = 0.f;
        if (mt < 3) {
            const float* Wrow = (mt == 0 ? Wnn : (mt == 1 ? Wno : WE)) + (size_t)j * KF;
            #pragma unroll
            for (int c = 0; c < 4; ++c) {
                float cc = 0.f;
                int k0 = c * KC;
                for (int k = k0; k < k0 + KC; ++k) {
                    float a = (k < KU) ? urow[k] : R32[k - KU];
                    cc = fmaf(a, Wrow[k], cc);
                }
                t = __fadd_rn(t, cc);
            }
            t = __fadd_rn(t, (mt == 0 ? bnn : (mt == 1 ? bno : bE))[j]);
        }
        float h2 = __shfl(t, 16 + e);
        float ee = __shfl(t, 32 + e);
        float m = -INFINITY;
        if (mt == 0)
            m = __fadd_rn(t, __fmul_rn(h2, noise[(size_t)s * NJ + j]));
        float v1 = m; int i1 = e;
        #pragma unroll
        for (int mk = 1; mk <= 8; mk <<= 1) {
            float ov = __shfl_xor(v1, mk);
            int oi = __shfl_xor(i1, mk);
            if (ov > v1 || (ov == v1 && oi < i1)) { v1 = ov; i1 = oi; }
        }
        float v2 = (mt == 0 && e == i1) ? -INFINITY : m;
        int i2 = (mt == 0 && e == i1) ? 64 : e;
        #pragma unroll
        for (int mk = 1; mk <= 8; mk <<= 1) {
            float ov = __shfl_xor(v2, mk);
            int oi = __shfl_xor(i2, mk);
            if (ov > v2 || (ov == v2 && oi < i2)) { v2 = ov; i2 = oi; }
        }
        float se = ee;
        #pragma unroll
        for (int mk = 1; mk <= 8; mk <<= 1) se += __shfl_xor(se, mk);
        float ev1 = __shfl(ee, i1);
        float ev2 = __shfl(ee, i2 & 15);
        if (l == 0) {
            double x1 = (v1 == 0.0f) ? -100000.0 : (double)v1;
            double x2 = (v2 == 0.0f) ? -100000.0 : (double)v2;
            double vmax = fmax(fmax(x1, x2), -100000.0);
            double g1 = exp(x1 - vmax), g2 = exp(x2 - vmax), gz = exp(-100000.0 - vmax);
            double den = g1 + g2 + 14.0 * gz;
            double num = g1 * (double)ev1 + g2 * (double)ev2
                       + gz * ((double)se - (double)ev1 - (double)ev2);
            out[si] = (float)(num / den * 0.0625);
        }
    }
}

// ---- fallback: proven round-5 ws-free kernel (bit-identical arithmetic) ----
__global__ __launch_bounds__(256) void k_base(
    const float* __restrict__ u, const float* __restrict__ noise,
    const float* __restrict__ Wnn, const float* __restrict__ Wno, const float* __restrict__ WE,
    const float* __restrict__ bnn, const float* __restrict__ bno, const float* __restrict__ bE,
    const float* __restrict__ h, const float* __restrict__ us, const float* __restrict__ ue,
    const float* __restrict__ Wr, const float* __restrict__ br,
    float* __restrict__ out)
{
    __shared__ __align__(16) float As[BM][PA];
    __shared__ __align__(16) float Ws[3][BK][PW];
    __shared__ float Rsh[512];

    const int tid = threadIdx.x;
    const int sr = tid >> 2, dl = tid & 3;
    const int jBase = blockIdx.x * 64;
    const int sBase = blockIdx.y * BM;
    const int myCol = dl * 16;

    for (int o = tid; o < 512; o += 256) Rsh[o] = chainR(h, us, ue, Wr, br, o);

    float t1[16] = {}, c1[16] = {}, t2[16] = {}, c2[16] = {}, tE[16] = {}, cE[16] = {};

    for (int kt = 0; kt < KF; kt += BK) {
        __syncthreads();
        if (kt < KU) {
            for (int idx = tid; idx < BM * BK; idx += 256) {
                int r = idx >> 5, c = idx & 31;
                As[r][c] = u[(size_t)(sBase + r) * KU + kt + c];
            }
        }
        for (int idx = tid; idx < 64 * BK; idx += 256) {
            int col = idx >> 5, kk = idx & 31;
            size_t off = (size_t)(jBase + col) * KF + kt + kk;
            Ws[0][kk][col] = Wnn[off];
            Ws[1][kk][col] = Wno[off];
            Ws[2][kk][col] = WE[off];
        }
        __syncthreads();
        const bool uReg = (kt < KU);
        for (int kk = 0; kk < BK; ++kk) {
            float a = uReg ? As[sr][kk] : Rsh[kt + kk - KU];
            #pragma unroll
            for (int q = 0; q < 4; ++q) {
                float4 w0 = *(const float4*)&Ws[0][kk][myCol + 4 * q];
                float4 w1 = *(const float4*)&Ws[1][kk][myCol + 4 * q];
                float4 w2 = *(const float4*)&Ws[2][kk][myCol + 4 * q];
                c1[4*q+0] = fmaf(a, w0.x, c1[4*q+0]);
                c1[4*q+1] = fmaf(a, w0.y, c1[4*q+1]);
                c1[4*q+2] = fmaf(a, w0.z, c1[4*q+2]);
                c1[4*q+3] = fmaf(a, w0.w, c1[4*q+3]);
                c2[4*q+0] = fmaf(a, w1.x, c2[4*q+0]);
                c2[4*q+1] = fmaf(a, w1.y, c2[4*q+1]);
                c2[4*q+2] = fmaf(a, w1.z, c2[4*q+2]);
                c2[4*q+3] = fmaf(a, w1.w, c2[4*q+3]);
                cE[4*q+0] = fmaf(a, w2.x, cE[4*q+0]);
                cE[4*q+1] = fmaf(a, w2.y, cE[4*q+1]);
                cE[4*q+2] = fmaf(a, w2.z, cE[4*q+2]);
                cE[4*q+3] = fmaf(a, w2.w, cE[4*q+3]);
            }
        }
        if (((kt + BK) % KC) == 0 || (kt + BK) == KF) {
            #pragma unroll
            for (int e = 0; e < 16; ++e) {
                t1[e] = __fadd_rn(t1[e], c1[e]); c1[e] = 0.f;
                t2[e] = __fadd_rn(t2[e], c2[e]); c2[e] = 0.f;
                tE[e] = __fadd_rn(tE[e], cE[e]); cE[e] = 0.f;
            }
        }
    }

    const int s = sBase + sr;
    const int jb = jBase + myCol;
    float m32[16]; double evv[16];
    #pragma unroll
    for (int e = 0; e < 16; ++e) {
        float h1 = __fadd_rn(t1[e], bnn[jb + e]);
        float h2 = __fadd_rn(t2[e], bno[jb + e]);
        float nz = noise[(size_t)s * NJ + jb + e];
        m32[e] = __fadd_rn(h1, __fmul_rn(h2, nz));
        evv[e] = (double)__fadd_rn(tE[e], bE[jb + e]);
    }
    int i1 = 0; float v1 = m32[0];
    #pragma unroll
    for (int e = 1; e < 16; ++e) if (m32[e] > v1) { v1 = m32[e]; i1 = e; }
    int i2 = -1; float v2 = -INFINITY;
    #pragma unroll
    for (int e = 0; e < 16; ++e) if (e != i1 && m32[e] > v2) { v2 = m32[e]; i2 = e; }
    double e1 = 0.0, e2 = 0.0, sumE = 0.0;
    #pragma unroll
    for (int e = 0; e < 16; ++e) {
        e1 = (e == i1) ? evv[e] : e1;
        e2 = (e == i2) ? evv[e] : e2;
        sumE += evv[e];
    }
    double x1 = (v1 == 0.0f) ? -100000.0 : (double)v1;
    double x2 = (v2 == 0.0f) ? -100000.0 : (double)v2;
    double vmax = fmax(fmax(x1, x2), -100000.0);
    double g1 = exp(x1 - vmax), g2 = exp(x2 - vmax), gz = exp(-100000.0 - vmax);
    double den = g1 + g2 + 14.0 * gz;
    double num = g1 * e1 + g2 * e2 + gz * (sumE - e1 - e2);
    out[(size_t)s * DIMD + (jBase >> 4) + dl] = (float)(num / den * 0.0625);
}

extern "C" void kernel_launch(void* const* d_in, const int* in_sizes, int n_in,
                              void* d_out, int out_size, void* d_ws, size_t ws_size,
                              hipStream_t stream) {
    (void)in_sizes; (void)n_in; (void)out_size;
    const float* h     = (const float*)d_in[0];
    const float* us    = (const float*)d_in[1];
    const float* ue    = (const float*)d_in[2];
    const float* u     = (const float*)d_in[3];
    const float* noise = (const float*)d_in[4];
    const float* Wnn   = (const float*)d_in[5];
    const float* bnn   = (const float*)d_in[6];
    const float* Wno   = (const float*)d_in[7];
    const float* bno   = (const float*)d_in[8];
    const float* WE    = (const float*)d_in[9];
    const float* bE    = (const float*)d_in[10];
    const float* Wr    = (const float*)d_in[11];
    const float* br    = (const float*)d_in[12];
    float* out = (float*)d_out;

    if (ws_size >= WS_NEEDED) {
        char* ws = (char*)d_ws;
        float* Rws  = (float*)(ws + WS_R);
        float* Bc   = (float*)(ws + WS_BC);
        float* Bce  = (float*)(ws + WS_BCE);
        int*   cnt  = (int*)(ws + WS_CNT);
        int*   wl   = (int*)(ws + WS_WL);
        ushort* uhi = (ushort*)(ws + WS_UHI);
        ushort* ulo = (ushort*)(ws + WS_ULO);
        ushort* whi = (ushort*)(ws + WS_WHI);
        ushort* wlo = (ushort*)(ws + WS_WLO);
        ushort* weh = (ushort*)(ws + WS_WEH);

        hipLaunchKernelGGL(k_R32, dim3(2), dim3(256), 0, stream, h, us, ue, Wr, br, Rws);
        hipLaunchKernelGGL(k_prep_u, dim3(SEQL * KU / 8 / 256), dim3(256), 0, stream, u, uhi, ulo);
        hipLaunchKernelGGL(k_prep_w, dim3(2 * NJ * KU / 8 / 256), dim3(256), 0, stream, Wnn, Wno, whi, wlo);
        hipLaunchKernelGGL(k_prep_we, dim3(NJ * KU / 8 / 256), dim3(256), 0, stream, WE, weh);
        hipLaunchKernelGGL(k_bc, dim3(4096), dim3(256), 0, stream, Rws, Wnn, Wno, bnn, bno, Bc);
        hipLaunchKernelGGL(k_bce, dim3(2048), dim3(256), 0, stream, Rws, WE, bE, Bce);
        hipLaunchKernelGGL(k_zero, dim3(1), dim3(1), 0, stream, cnt);
        hipLaunchKernelGGL(k_m, dim3(NJ / 64, SEQL / 128), dim3(256), 0, stream,
                           uhi, ulo, whi, wlo, weh, noise, Bc, Bce, cnt, wl, out);
        hipLaunchKernelGGL(k_repair, dim3(512), dim3(256), 0, stream,
                           u, noise, Wnn, Wno, WE, bnn, bno, bE, Rws, cnt, wl, out);
    } else {
        hipLaunchKernelGGL(k_base, dim3(NJ / 64, SEQL / BM), dim3(256), 0, stream,
                           u, noise, Wnn, Wno, WE, bnn, bno, bE,
                           h, us, ue, Wr, br, out);
    }
}

// Round 11
// 1302.832 us; speedup vs baseline: 1.6401x; 1.1329x over previous
//
#include <hip/hip_runtime.h>
#include <hip/hip_bf16.h>
#include <math.h>

#define DIMD 512
#define SEQL 4096
#define KU 1024
#define KF 1536
#define NJ 8192
#define KC 384          // OpenBLAS sgemm K-blocking (matched in round 5)
#define NTK 32          // KU/32 k-tiles

#define BM 64
#define BK 32
#define PA 33
#define PW 68

#define GAP_T 1e-3f

// ---- ws layout (bytes) ----
#define WS_R    0u          // 512 f32
#define WS_BC   4096u       // 2*8192 f32 (m-path combined bias, f64-folded)
#define WS_BCE  69632u      // 8192 f32 (e-path combined bias, f64-folded)
#define WS_CNT  102400u     // int counter
#define WS_WL   102656u     // worklist (2.1M ints max)
#define WS_UHI  8491264u    // 4096*1024 bf16, fragment order
#define WS_ULO  16879872u   // 4096*1024 bf16, fragment order
#define WS_WHI  25268480u   // 2*8192*1024 bf16 (Wnn,Wno hi), fragment order
#define WS_WLO  58822912u   // 2*8192*1024 bf16 (lo), fragment order
#define WS_WEH  92377344u   // 8192*1024 bf16 (W_E hi), fragment order
#define WS_NEEDED 109154560u

typedef __attribute__((ext_vector_type(8))) short bf16x8;
typedef __attribute__((ext_vector_type(4))) float f32x4;

__device__ __forceinline__ ushort f2bf(float f) {
    __hip_bfloat16 h = __float2bfloat16(f);
    return *reinterpret_cast<ushort*>(&h);
}
__device__ __forceinline__ float bf2f(ushort v) {
    unsigned int b = ((unsigned int)v) << 16;
    return __uint_as_float(b);
}

// ---- f32 R with the exact chunked fma chain (k-ascending, KC blocks) ----
__device__ __forceinline__ float chainR(
    const float* __restrict__ h, const float* __restrict__ us, const float* __restrict__ ue,
    const float* __restrict__ Wr, const float* __restrict__ br, int o)
{
    float accT = 0.f;
    for (int k0 = 0; k0 < 2560; k0 += KC) {
        int ke = (k0 + KC < 2560) ? k0 + KC : 2560;
        float accC = 0.f;
        for (int k = k0; k < ke; ++k) {
            float xv = (k < 1536) ? h[k] : (k < 2048) ? us[k - 1536] : ue[k - 2048];
            accC = fmaf(xv, Wr[(size_t)o * 2560 + k], accC);
        }
        accT = __fadd_rn(accT, accC);
    }
    return __fadd_rn(accT, br[o]);
}

__global__ __launch_bounds__(256) void k_R32(
    const float* __restrict__ h, const float* __restrict__ us, const float* __restrict__ ue,
    const float* __restrict__ Wr, const float* __restrict__ br,
    float* __restrict__ Rout, int* __restrict__ cnt)
{
    if (blockIdx.x == 0 && threadIdx.x == 0) *cnt = 0;
    int o = blockIdx.x * 256 + threadIdx.x;
    Rout[o] = chainR(h, us, ue, Wr, br, o);
}

// ---- prep u: block per s16-tile; coalesced read -> LDS -> coalesced frag write ----
#define LPAD 1032
__global__ __launch_bounds__(256) void k_prep_u(
    const float* __restrict__ u, ushort* __restrict__ uhi, ushort* __restrict__ ulo)
{
    __shared__ ushort hs[16 * LPAD], ls[16 * LPAD];
    const int tid = threadIdx.x;
    const int t16 = blockIdx.x;
    #pragma unroll
    for (int it = 0; it < 16; ++it) {
        int k = tid * 4;                       // row = it
        float4 v = *(const float4*)&u[((size_t)t16 * 16 + it) * KU + k];
        ushort4 a, b;
        a.x = f2bf(v.x); b.x = f2bf(v.x - bf2f(a.x));
        a.y = f2bf(v.y); b.y = f2bf(v.y - bf2f(a.y));
        a.z = f2bf(v.z); b.z = f2bf(v.z - bf2f(a.z));
        a.w = f2bf(v.w); b.w = f2bf(v.w - bf2f(a.w));
        *(ushort4*)&hs[it * LPAD + k] = a;
        *(ushort4*)&ls[it * LPAD + k] = b;
    }
    __syncthreads();
    #pragma unroll
    for (int ct = 0; ct < 8; ++ct) {
        int c = ct * 256 + tid;                // 2048 chunks
        int k32 = c >> 6, l = c & 63;
        int src = (l & 15) * LPAD + k32 * 32 + (l >> 4) * 8;
        size_t dst = (((size_t)t16 * NTK + k32) * 64 + l) * 8;
        *(uint4*)&uhi[dst] = *(const uint4*)&hs[src];
        *(uint4*)&ulo[dst] = *(const uint4*)&ls[src];
    }
}

// ---- prep Wnn/Wno: block per (mat, j16); hi+lo ----
__global__ __launch_bounds__(256) void k_prep_w(
    const float* __restrict__ Wnn, const float* __restrict__ Wno,
    ushort* __restrict__ whi, ushort* __restrict__ wlo)
{
    __shared__ ushort hs[16 * LPAD], ls[16 * LPAD];
    const int tid = threadIdx.x;
    const int mat = blockIdx.x >> 9, j16 = blockIdx.x & 511;
    const float* W = mat ? Wno : Wnn;
    #pragma unroll
    for (int it = 0; it < 16; ++it) {
        int k = tid * 4;
        float4 v = *(const float4*)&W[((size_t)j16 * 16 + it) * KF + k];
        ushort4 a, b;
        a.x = f2bf(v.x); b.x = f2bf(v.x - bf2f(a.x));
        a.y = f2bf(v.y); b.y = f2bf(v.y - bf2f(a.y));
        a.z = f2bf(v.z); b.z = f2bf(v.z - bf2f(a.z));
        a.w = f2bf(v.w); b.w = f2bf(v.w - bf2f(a.w));
        *(ushort4*)&hs[it * LPAD + k] = a;
        *(ushort4*)&ls[it * LPAD + k] = b;
    }
    __syncthreads();
    #pragma unroll
    for (int ct = 0; ct < 8; ++ct) {
        int c = ct * 256 + tid;
        int k32 = c >> 6, l = c & 63;
        int src = (l & 15) * LPAD + k32 * 32 + (l >> 4) * 8;
        size_t dst = ((((size_t)mat * 512 + j16) * NTK + k32) * 64 + l) * 8;
        *(uint4*)&whi[dst] = *(const uint4*)&hs[src];
        *(uint4*)&wlo[dst] = *(const uint4*)&ls[src];
    }
}

// ---- prep W_E: block per j16; hi only ----
__global__ __launch_bounds__(256) void k_prep_we(
    const float* __restrict__ WE, ushort* __restrict__ weh)
{
    __shared__ ushort hs[16 * LPAD];
    const int tid = threadIdx.x;
    const int j16 = blockIdx.x;
    #pragma unroll
    for (int it = 0; it < 16; ++it) {
        int k = tid * 4;
        float4 v = *(const float4*)&WE[((size_t)j16 * 16 + it) * KF + k];
        ushort4 a;
        a.x = f2bf(v.x); a.y = f2bf(v.y); a.z = f2bf(v.z); a.w = f2bf(v.w);
        *(ushort4*)&hs[it * LPAD + k] = a;
    }
    __syncthreads();
    #pragma unroll
    for (int ct = 0; ct < 8; ++ct) {
        int c = ct * 256 + tid;
        int k32 = c >> 6, l = c & 63;
        int src = (l & 15) * LPAD + k32 * 32 + (l >> 4) * 8;
        size_t dst = (((size_t)j16 * NTK + k32) * 64 + l) * 8;
        *(uint4*)&weh[dst] = *(const uint4*)&hs[src];
    }
}

// ---- merged bias: mat 0,1 -> Bc; mat 2 -> Bce (f64 fold, wave per output) ----
__global__ __launch_bounds__(256) void k_bias(
    const float* __restrict__ R32,
    const float* __restrict__ Wnn, const float* __restrict__ Wno, const float* __restrict__ WE,
    const float* __restrict__ bnn, const float* __restrict__ bno, const float* __restrict__ bE,
    float* __restrict__ Bc, float* __restrict__ Bce)
{
    int wid = blockIdx.x * 4 + (threadIdx.x >> 6);   // 0..24575
    int l = threadIdx.x & 63;
    int mat = wid >> 13, j = wid & 8191;
    const float* W = (mat == 0) ? Wnn : (mat == 1) ? Wno : WE;
    const float* b = (mat == 0) ? bnn : (mat == 1) ? bno : bE;
    double acc = 0.0;
    for (int k = 1024 + l; k < 1536; k += 64)
        acc += (double)R32[k - KU] * (double)W[(size_t)j * KF + k];
    for (int off = 32; off > 0; off >>= 1) acc += __shfl_down(acc, off);
    if (l == 0) {
        float r = (float)(acc + (double)b[j]);
        if (mat < 2) Bc[wid] = r; else Bce[j] = r;
    }
}

// ---- fused m+e kernel: linear fragment LDS, shuffle gate (no LDS epilogue) ----
struct MSt {
    ushort u1[4096], u2[4096];    // 8 s16-tiles x 64 lanes x 8
    ushort w1[4096], w2[4096];    // (2 mats x 4 j16-tiles) x 64 x 8
    ushort we[2048];              // 4 j16-tiles x 64 x 8
};                                // 36864 B

__global__ __launch_bounds__(256, 3) void k_m(
    const ushort* __restrict__ uhi, const ushort* __restrict__ ulo,
    const ushort* __restrict__ whi, const ushort* __restrict__ wlo,
    const ushort* __restrict__ weh,
    const float* __restrict__ noise,
    const float* __restrict__ Bc, const float* __restrict__ Bce,
    int* __restrict__ cnt, int* __restrict__ wl, float* __restrict__ out)
{
    __shared__ MSt sm;
    const int tid = threadIdx.x;
    const int w = tid >> 6, l = tid & 63;
    const int wm = w >> 1, wn = w & 1;
    const int lr = l & 15, lq = l >> 4;
    const int l8 = l * 8;
    const int sBase = blockIdx.y * 128;
    const int sB16 = blockIdx.y * 8;
    const int jBase = blockIdx.x * 64;
    const int jB16 = blockIdx.x * 4;
    const int dBase = jBase >> 4;

    f32x4 acc1[4][2] = {}, acc2[4][2] = {}, accE[4][2] = {};

    for (int kt = 0; kt < NTK; ++kt) {
        __syncthreads();
        #pragma unroll
        for (int it = 0; it < 4; ++it) {            // u: 1024 x 16B
            int c = tid + it * 256;
            int buf = c >> 9, rem = c & 511;
            size_t g = (((size_t)(sB16 + (rem >> 6)) * NTK + kt) * 64 + (rem & 63)) * 8;
            const ushort* src = buf ? ulo : uhi;
            ushort* dst = (buf ? sm.u2 : sm.u1) + rem * 8;
            *(uint4*)dst = *(const uint4*)&src[g];
        }
        #pragma unroll
        for (int it = 0; it < 4; ++it) {            // w: 1024 x 16B
            int c = tid + it * 256;
            int buf = c >> 9, rem = c & 511;
            int mt = rem >> 8, jt = (rem >> 6) & 3;
            size_t g = ((((size_t)mt * 512 + jB16 + jt) * NTK + kt) * 64 + (rem & 63)) * 8;
            const ushort* src = buf ? wlo : whi;
            ushort* dst = (buf ? sm.w2 : sm.w1) + rem * 8;
            *(uint4*)dst = *(const uint4*)&src[g];
        }
        {                                           // we: 256 x 16B
            int jt = tid >> 6;
            size_t g = (((size_t)(jB16 + jt) * NTK + kt) * 64 + (tid & 63)) * 8;
            *(uint4*)&sm.we[tid * 8] = *(const uint4*)&weh[g];
        }
        __syncthreads();
        bf16x8 a1[4], a2[4];
        #pragma unroll
        for (int i = 0; i < 4; ++i) {
            int base = (wm * 4 + i) * 512 + l8;
            a1[i] = *(const bf16x8*)&sm.u1[base];
            a2[i] = *(const bf16x8*)&sm.u2[base];
        }
        #pragma unroll
        for (int n = 0; n < 2; ++n) {
            int jloc = wn * 2 + n;
            {   // mat 0 -> acc1 (only 2 w-frags live)
                bf16x8 p1 = *(const bf16x8*)&sm.w1[jloc * 512 + l8];
                bf16x8 p2 = *(const bf16x8*)&sm.w2[jloc * 512 + l8];
                #pragma unroll
                for (int i = 0; i < 4; ++i) {
                    acc1[i][n] = __builtin_amdgcn_mfma_f32_16x16x32_bf16(a1[i], p1, acc1[i][n], 0, 0, 0);
                    acc1[i][n] = __builtin_amdgcn_mfma_f32_16x16x32_bf16(a1[i], p2, acc1[i][n], 0, 0, 0);
                    acc1[i][n] = __builtin_amdgcn_mfma_f32_16x16x32_bf16(a2[i], p1, acc1[i][n], 0, 0, 0);
                }
            }
            {   // mat 1 -> acc2
                bf16x8 p1 = *(const bf16x8*)&sm.w1[(4 + jloc) * 512 + l8];
                bf16x8 p2 = *(const bf16x8*)&sm.w2[(4 + jloc) * 512 + l8];
                #pragma unroll
                for (int i = 0; i < 4; ++i) {
                    acc2[i][n] = __builtin_amdgcn_mfma_f32_16x16x32_bf16(a1[i], p1, acc2[i][n], 0, 0, 0);
                    acc2[i][n] = __builtin_amdgcn_mfma_f32_16x16x32_bf16(a1[i], p2, acc2[i][n], 0, 0, 0);
                    acc2[i][n] = __builtin_amdgcn_mfma_f32_16x16x32_bf16(a2[i], p1, acc2[i][n], 0, 0, 0);
                }
            }
            {   // E -> accE
                bf16x8 pe = *(const bf16x8*)&sm.we[jloc * 512 + l8];
                #pragma unroll
                for (int i = 0; i < 4; ++i)
                    accE[i][n] = __builtin_amdgcn_mfma_f32_16x16x32_bf16(a1[i], pe, accE[i][n], 0, 0, 0);
            }
        }
    }

    // ---- epilogue: in-register gate via lr-group butterflies ----
    float bc1[2], bc2[2], be[2];
    #pragma unroll
    for (int n = 0; n < 2; ++n) {
        int col = jBase + wn * 32 + n * 16 + lr;
        bc1[n] = Bc[col];
        bc2[n] = Bc[NJ + col];
        be[n]  = Bce[col];
    }
    const int gbase = l & 48;       // lr-group base lane
    #pragma unroll
    for (int i = 0; i < 4; ++i)
        #pragma unroll
        for (int n = 0; n < 2; ++n) {
            int colL = wn * 32 + n * 16 + lr;
            int dloc = wn * 2 + n;
            #pragma unroll
            for (int r = 0; r < 4; ++r) {
                int rowL = wm * 64 + i * 16 + lq * 4 + r;
                float m1 = acc1[i][n][r] + bc1[n];
                float m2 = acc2[i][n][r] + bc2[n];
                float nz = noise[(size_t)(sBase + rowL) * NJ + jBase + colL];
                float m  = fmaf(m2, nz, m1);
                float ev = accE[i][n][r] + be[n];
                // top-1 (index-stable)
                float v1 = m; int i1 = lr;
                #pragma unroll
                for (int mk = 1; mk <= 8; mk <<= 1) {
                    float ov = __shfl_xor(v1, mk);
                    int oi = __shfl_xor(i1, mk);
                    if (ov > v1 || (ov == v1 && oi < i1)) { v1 = ov; i1 = oi; }
                }
                // top-2
                float v2 = (lr == i1) ? -INFINITY : m;
                int i2 = (lr == i1) ? 64 : lr;
                #pragma unroll
                for (int mk = 1; mk <= 8; mk <<= 1) {
                    float ov = __shfl_xor(v2, mk);
                    int oi = __shfl_xor(i2, mk);
                    if (ov > v2 || (ov == v2 && oi < i2)) { v2 = ov; i2 = oi; }
                }
                // top-3 value
                float v3 = (lr == i1 || lr == i2) ? -INFINITY : m;
                #pragma unroll
                for (int mk = 1; mk <= 8; mk <<= 1)
                    v3 = fmaxf(v3, __shfl_xor(v3, mk));
                float ev1 = __shfl(ev, gbase + i1);
                float ev2 = __shfl(ev, gbase + (i2 & 15));
                if (lr == 0) {
                    int gidx = (sBase + rowL) * DIMD + dBase + dloc;
                    bool flg = (v2 - v3 < GAP_T) || (fabsf(v1) < GAP_T) || (fabsf(v2) < GAP_T);
                    if (flg) {
                        int pos = atomicAdd(cnt, 1);
                        wl[pos] = gidx;
                    }
                    double x1 = (double)v1, x2 = (double)v2;
                    double vmax = fmax(x1, x2);
                    double g1 = exp(x1 - vmax), g2 = exp(x2 - vmax);
                    double num = g1 * (double)ev1 + g2 * (double)ev2;
                    out[gidx] = (float)(num / (g1 + g2) * 0.0625);
                }
            }
        }
}

// ---- repair: one wave per flagged site; lane = (expert, mat) exact chain ----
__global__ __launch_bounds__(256) void k_repair(
    const float* __restrict__ u, const float* __restrict__ noise,
    const float* __restrict__ Wnn, const float* __restrict__ Wno, const float* __restrict__ WE,
    const float* __restrict__ bnn, const float* __restrict__ bno, const float* __restrict__ bE,
    const float* __restrict__ R32,
    const int* __restrict__ cnt, const int* __restrict__ wl, float* __restrict__ out)
{
    const int l = threadIdx.x & 63;
    const int e = l & 15, mt = l >> 4;          // mt in 0..3 (3 idle)
    const int wid = (blockIdx.x * 256 + threadIdx.x) >> 6;
    const int NW = (512 * 256) >> 6;
    const int n = *cnt;

    for (int i = wid; i < n; i += NW) {
        int si = wl[i];
        int s = si >> 9, d = si & 511;
        int j = d * 16 + e;
        const float* urow = u + (size_t)s * KU;
        float t = 0.f;
        if (mt < 3) {
            const float* Wrow = (mt == 0 ? Wnn : (mt == 1 ? Wno : WE)) + (size_t)j * KF;
            #pragma unroll
            for (int c = 0; c < 4; ++c) {
                float cc = 0.f;
                int k0 = c * KC;
                for (int k = k0; k < k0 + KC; ++k) {
                    float a = (k < KU) ? urow[k] : R32[k - KU];
                    cc = fmaf(a, Wrow[k], cc);
                }
                t = __fadd_rn(t, cc);
            }
            t = __fadd_rn(t, (mt == 0 ? bnn : (mt == 1 ? bno : bE))[j]);
        }
        float h2 = __shfl(t, 16 + e);
        float ee = __shfl(t, 32 + e);
        float m = -INFINITY;
        if (mt == 0)
            m = __fadd_rn(t, __fmul_rn(h2, noise[(size_t)s * NJ + j]));
        float v1 = m; int i1 = e;
        #pragma unroll
        for (int mk = 1; mk <= 8; mk <<= 1) {
            float ov = __shfl_xor(v1, mk);
            int oi = __shfl_xor(i1, mk);
            if (ov > v1 || (ov == v1 && oi < i1)) { v1 = ov; i1 = oi; }
        }
        float v2 = (mt == 0 && e == i1) ? -INFINITY : m;
        int i2 = (mt == 0 && e == i1) ? 64 : e;
        #pragma unroll
        for (int mk = 1; mk <= 8; mk <<= 1) {
            float ov = __shfl_xor(v2, mk);
            int oi = __shfl_xor(i2, mk);
            if (ov > v2 || (ov == v2 && oi < i2)) { v2 = ov; i2 = oi; }
        }
        float se = ee;
        #pragma unroll
        for (int mk = 1; mk <= 8; mk <<= 1) se += __shfl_xor(se, mk);
        float ev1 = __shfl(ee, i1);
        float ev2 = __shfl(ee, i2 & 15);
        if (l == 0) {
            double x1 = (v1 == 0.0f) ? -100000.0 : (double)v1;
            double x2 = (v2 == 0.0f) ? -100000.0 : (double)v2;
            double vmax = fmax(fmax(x1, x2), -100000.0);
            double g1 = exp(x1 - vmax), g2 = exp(x2 - vmax), gz = exp(-100000.0 - vmax);
            double den = g1 + g2 + 14.0 * gz;
            double num = g1 * (double)ev1 + g2 * (double)ev2
                       + gz * ((double)se - (double)ev1 - (double)ev2);
            out[si] = (float)(num / den * 0.0625);
        }
    }
}

// ---- fallback: proven round-5 ws-free kernel (bit-identical arithmetic) ----
__global__ __launch_bounds__(256) void k_base(
    const float* __restrict__ u, const float* __restrict__ noise,
    const float* __restrict__ Wnn, const float* __restrict__ Wno, const float* __restrict__ WE,
    const float* __restrict__ bnn, const float* __restrict__ bno, const float* __restrict__ bE,
    const float* __restrict__ h, const float* __restrict__ us, const float* __restrict__ ue,
    const float* __restrict__ Wr, const float* __restrict__ br,
    float* __restrict__ out)
{
    __shared__ __align__(16) float As[BM][PA];
    __shared__ __align__(16) float Ws[3][BK][PW];
    __shared__ float Rsh[512];

    const int tid = threadIdx.x;
    const int sr = tid >> 2, dl = tid & 3;
    const int jBase = blockIdx.x * 64;
    const int sBase = blockIdx.y * BM;
    const int myCol = dl * 16;

    for (int o = tid; o < 512; o += 256) Rsh[o] = chainR(h, us, ue, Wr, br, o);

    float t1[16] = {}, c1[16] = {}, t2[16] = {}, c2[16] = {}, tE[16] = {}, cE[16] = {};

    for (int kt = 0; kt < KF; kt += BK) {
        __syncthreads();
        if (kt < KU) {
            for (int idx = tid; idx < BM * BK; idx += 256) {
                int r = idx >> 5, c = idx & 31;
                As[r][c] = u[(size_t)(sBase + r) * KU + kt + c];
            }
        }
        for (int idx = tid; idx < 64 * BK; idx += 256) {
            int col = idx >> 5, kk = idx & 31;
            size_t off = (size_t)(jBase + col) * KF + kt + kk;
            Ws[0][kk][col] = Wnn[off];
            Ws[1][kk][col] = Wno[off];
            Ws[2][kk][col] = WE[off];
        }
        __syncthreads();
        const bool uReg = (kt < KU);
        for (int kk = 0; kk < BK; ++kk) {
            float a = uReg ? As[sr][kk] : Rsh[kt + kk - KU];
            #pragma unroll
            for (int q = 0; q < 4; ++q) {
                float4 w0 = *(const float4*)&Ws[0][kk][myCol + 4 * q];
                float4 w1 = *(const float4*)&Ws[1][kk][myCol + 4 * q];
                float4 w2 = *(const float4*)&Ws[2][kk][myCol + 4 * q];
                c1[4*q+0] = fmaf(a, w0.x, c1[4*q+0]);
                c1[4*q+1] = fmaf(a, w0.y, c1[4*q+1]);
                c1[4*q+2] = fmaf(a, w0.z, c1[4*q+2]);
                c1[4*q+3] = fmaf(a, w0.w, c1[4*q+3]);
                c2[4*q+0] = fmaf(a, w1.x, c2[4*q+0]);
                c2[4*q+1] = fmaf(a, w1.y, c2[4*q+1]);
                c2[4*q+2] = fmaf(a, w1.z, c2[4*q+2]);
                c2[4*q+3] = fmaf(a, w1.w, c2[4*q+3]);
                cE[4*q+0] = fmaf(a, w2.x, cE[4*q+0]);
                cE[4*q+1] = fmaf(a, w2.y, cE[4*q+1]);
                cE[4*q+2] = fmaf(a, w2.z, cE[4*q+2]);
                cE[4*q+3] = fmaf(a, w2.w, cE[4*q+3]);
            }
        }
        if (((kt + BK) % KC) == 0 || (kt + BK) == KF) {
            #pragma unroll
            for (int e = 0; e < 16; ++e) {
                t1[e] = __fadd_rn(t1[e], c1[e]); c1[e] = 0.f;
                t2[e] = __fadd_rn(t2[e], c2[e]); c2[e] = 0.f;
                tE[e] = __fadd_rn(tE[e], cE[e]); cE[e] = 0.f;
            }
        }
    }

    const int s = sBase + sr;
    const int jb = jBase + myCol;
    float m32[16]; double evv[16];
    #pragma unroll
    for (int e = 0; e < 16; ++e) {
        float h1 = __fadd_rn(t1[e], bnn[jb + e]);
        float h2 = __fadd_rn(t2[e], bno[jb + e]);
        float nz = noise[(size_t)s * NJ + jb + e];
        m32[e] = __fadd_rn(h1, __fmul_rn(h2, nz));
        evv[e] = (double)__fadd_rn(tE[e], bE[jb + e]);
    }
    int i1 = 0; float v1 = m32[0];
    #pragma unroll
    for (int e = 1; e < 16; ++e) if (m32[e] > v1) { v1 = m32[e]; i1 = e; }
    int i2 = -1; float v2 = -INFINITY;
    #pragma unroll
    for (int e = 0; e < 16; ++e) if (e != i1 && m32[e] > v2) { v2 = m32[e]; i2 = e; }
    double e1 = 0.0, e2 = 0.0, sumE = 0.0;
    #pragma unroll
    for (int e = 0; e < 16; ++e) {
        e1 = (e == i1) ? evv[e] : e1;
        e2 = (e == i2) ? evv[e] : e2;
        sumE += evv[e];
    }
    double x1 = (v1 == 0.0f) ? -100000.0 : (double)v1;
    double x2 = (v2 == 0.0f) ? -100000.0 : (double)v2;
    double vmax = fmax(fmax(x1, x2), -100000.0);
    double g1 = exp(x1 - vmax), g2 = exp(x2 - vmax), gz = exp(-100000.0 - vmax);
    double den = g1 + g2 + 14.0 * gz;
    double num = g1 * e1 + g2 * e2 + gz * (sumE - e1 - e2);
    out[(size_t)s * DIMD + (jBase >> 4) + dl] = (float)(num / den * 0.0625);
}

extern "C" void kernel_launch(void* const* d_in, const int* in_sizes, int n_in,
                              void* d_out, int out_size, void* d_ws, size_t ws_size,
                              hipStream_t stream) {
    (void)in_sizes; (void)n_in; (void)out_size;
    const float* h     = (const float*)d_in[0];
    const float* us    = (const float*)d_in[1];
    const float* ue    = (const float*)d_in[2];
    const float* u     = (const float*)d_in[3];
    const float* noise = (const float*)d_in[4];
    const float* Wnn   = (const float*)d_in[5];
    const float* bnn   = (const float*)d_in[6];
    const float* Wno   = (const float*)d_in[7];
    const float* bno   = (const float*)d_in[8];
    const float* WE    = (const float*)d_in[9];
    const float* bE    = (const float*)d_in[10];
    const float* Wr    = (const float*)d_in[11];
    const float* br    = (const float*)d_in[12];
    float* out = (float*)d_out;

    if (ws_size >= WS_NEEDED) {
        char* ws = (char*)d_ws;
        float* Rws  = (float*)(ws + WS_R);
        float* Bc   = (float*)(ws + WS_BC);
        float* Bce  = (float*)(ws + WS_BCE);
        int*   cnt  = (int*)(ws + WS_CNT);
        int*   wl   = (int*)(ws + WS_WL);
        ushort* uhi = (ushort*)(ws + WS_UHI);
        ushort* ulo = (ushort*)(ws + WS_ULO);
        ushort* whi = (ushort*)(ws + WS_WHI);
        ushort* wlo = (ushort*)(ws + WS_WLO);
        ushort* weh = (ushort*)(ws + WS_WEH);

        hipLaunchKernelGGL(k_R32, dim3(2), dim3(256), 0, stream, h, us, ue, Wr, br, Rws, cnt);
        hipLaunchKernelGGL(k_prep_u, dim3(SEQL / 16), dim3(256), 0, stream, u, uhi, ulo);
        hipLaunchKernelGGL(k_prep_w, dim3(2 * NJ / 16), dim3(256), 0, stream, Wnn, Wno, whi, wlo);
        hipLaunchKernelGGL(k_prep_we, dim3(NJ / 16), dim3(256), 0, stream, WE, weh);
        hipLaunchKernelGGL(k_bias, dim3(6144), dim3(256), 0, stream,
                           Rws, Wnn, Wno, WE, bnn, bno, bE, Bc, Bce);
        hipLaunchKernelGGL(k_m, dim3(NJ / 64, SEQL / 128), dim3(256), 0, stream,
                           uhi, ulo, whi, wlo, weh, noise, Bc, Bce, cnt, wl, out);
        hipLaunchKernelGGL(k_repair, dim3(512), dim3(256), 0, stream,
                           u, noise, Wnn, Wno, WE, bnn, bno, bE, Rws, cnt, wl, out);
    } else {
        hipLaunchKernelGGL(k_base, dim3(NJ / 64, SEQL / BM), dim3(256), 0, stream,
                           u, noise, Wnn, Wno, WE, bnn, bno, bE,
                           h, us, ue, Wr, br, out);
    }
}